// Round 1
// baseline (440.427 us; speedup 1.0000x reference)
//
#include <hip/hip_runtime.h>
#include <hip/hip_bf16.h>

// PSWarpHead round 7. Pipeline change: conv2 (1x1, 28->28) commutes with
// bilinear sampling (both linear), so fold conv2 into conv1's epilogue as an
// fp32 wave-cooperative matvec (LDS tile transpose + dot28 per pixel).
//   transpose: fp32 x [b][c][hw] -> bf16 xT [b][hw][c]   (unchanged, validated)
//   conv1: MFMA main loop unchanged; epilogue = BN+relu -> LDS 16x32 tile ->
//          fp32 28x28 matvec (same op order class as old dot28) -> feat2[px][28]
//   sample: 4-corner SCALAR gather of feat2 (was 4x dot28 = 112 fp32 loads/lane)
// feat2 fp32 [b][px][28] = 15.77 MB (reuses old feat1 slot). ws within 90.26 MB.

#define WDIM 176
#define HDIM 200
#define HWDIM 35200
#define CIN 256
#define PDIM 28
#define NBOX 2048

typedef __attribute__((ext_vector_type(8))) short bf16x8;
typedef __attribute__((ext_vector_type(4))) float floatx4;

__device__ __forceinline__ unsigned short f2bf(float f) {
    unsigned int u; __builtin_memcpy(&u, &f, 4);
    unsigned int r = u + 0x7FFFu + ((u >> 16) & 1u);   // RNE
    return (unsigned short)(r >> 16);
}

// ---------- transpose: fp32 x [b][c][hw] -> bf16 xT [b][hw][c] ----------
__global__ __launch_bounds__(256) void transpose_kernel(const float* __restrict__ x,
                                                        unsigned short* __restrict__ xT) {
    __shared__ unsigned short tile[32][80];
    int b = blockIdx.z, c0 = blockIdx.y * 32, px0 = blockIdx.x * 64;
    int t = threadIdx.x;
    int c_l = t >> 3, pxg = (t & 7) * 8;
    const float* sp = x + (long)(b * CIN + c0 + c_l) * HWDIM + px0 + pxg;
    float4 a = ((const float4*)sp)[0], bq = ((const float4*)sp)[1];
    tile[c_l][pxg + 0] = f2bf(a.x);  tile[c_l][pxg + 1] = f2bf(a.y);
    tile[c_l][pxg + 2] = f2bf(a.z);  tile[c_l][pxg + 3] = f2bf(a.w);
    tile[c_l][pxg + 4] = f2bf(bq.x); tile[c_l][pxg + 5] = f2bf(bq.y);
    tile[c_l][pxg + 6] = f2bf(bq.z); tile[c_l][pxg + 7] = f2bf(bq.w);
    __syncthreads();
    int px_l = t >> 2, cg = (t & 3) * 8;
    ushort4 o0, o1;
    o0.x = tile[cg + 0][px_l]; o0.y = tile[cg + 1][px_l];
    o0.z = tile[cg + 2][px_l]; o0.w = tile[cg + 3][px_l];
    o1.x = tile[cg + 4][px_l]; o1.y = tile[cg + 5][px_l];
    o1.z = tile[cg + 6][px_l]; o1.w = tile[cg + 7][px_l];
    long dst = (long)(b * HWDIM + px0 + px_l) * CIN + c0 + cg;
    *(ushort4*)(xT + dst) = o0;
    *(ushort4*)(xT + dst + 4) = o1;
}

// ---------- prep: BwT[tap][n(32,pad0)][c] bf16; BN fold (fp32 in) ----------
__global__ void prep_kernel(const float* __restrict__ w1,
                            const float* __restrict__ g, const float* __restrict__ bt,
                            const float* __restrict__ mn, const float* __restrict__ vr,
                            unsigned short* __restrict__ BwT,
                            float* __restrict__ scale, float* __restrict__ shift) {
    int idx = blockIdx.x * 256 + threadIdx.x;
    if (idx < 9 * 32 * 256) {
        int tap = idx >> 13;
        int r = idx & 8191;
        int n = r >> 8, c = r & 255;
        BwT[idx] = (n < PDIM) ? f2bf(w1[n * 2304 + c * 9 + tap]) : (unsigned short)0;
    } else if (idx < 73728 + 32) {
        int p = idx - 73728;
        if (p < PDIM) {
            float inv = g[p] / sqrtf(vr[p] + 1e-3f);
            scale[p] = inv;
            shift[p] = bt[p] - mn[p] * inv;
        } else { scale[p] = 0.f; shift[p] = 0.f; }
    }
}

// ---------- conv1 (MFMA) + fused BN/relu/conv2 epilogue -> feat2[px][28] ----------
// block = (b,y) row: 6 waves, wave w -> px [w*32, w*32+32) (wave 5: 16 px).
__global__ __launch_bounds__(384) void conv1_kernel(const unsigned short* __restrict__ xT,
                                                    const unsigned short* __restrict__ BwT,
                                                    const float* __restrict__ scale,
                                                    const float* __restrict__ shift,
                                                    const float* __restrict__ w2,
                                                    float* __restrict__ feat2) {
    // per-wave fp32 tile for the conv2 matvec: 16 px rows x 32 ch, stride 36
    // (144 B rows -> 16B-aligned float4 reads; write banks 2-way max = free)
    __shared__ float t2[6][16][36];

    int y = blockIdx.x, b = blockIdx.y;
    int lane = threadIdx.x & 63, w = threadIdx.x >> 6;
    int nmt = (w == 5) ? 1 : 2;
    int lm = lane & 15, kg = lane >> 4;
    int pxb = w * 32;

    // hoisted per-(mt, dx) lane column + validity
    int  xcol[2][3];
    bool xval[2][3];
#pragma unroll
    for (int mt = 0; mt < 2; mt++) {
#pragma unroll
        for (int d = 0; d < 3; d++) {
            int xp = pxb + mt * 16 + lm + (d - 1);
            bool v = (xp >= 0) && (xp < WDIM);
            xval[mt][d] = v;
            xcol[mt][d] = v ? xp : 0;
        }
    }

    floatx4 acc[2][2] = {{{0.f,0.f,0.f,0.f},{0.f,0.f,0.f,0.f}},
                         {{0.f,0.f,0.f,0.f},{0.f,0.f,0.f,0.f}}};

    for (int j = 0; j < 8; j++) {
        int cofs = j * 32 + kg * 8;
#pragma unroll
        for (int tap = 0; tap < 9; tap++) {
            int dy = tap / 3 - 1, d = tap % 3;
            int yp = y + dy;
            if (yp < 0 || yp >= HDIM) continue;          // block-uniform
            long rowpx = (long)(b * HDIM + yp) * WDIM;
            const unsigned short* bp = BwT + ((tap * 32 + lm) << 8) + cofs;
            bf16x8 b0 = *(const bf16x8*)bp;
            bf16x8 b1 = *(const bf16x8*)(bp + 4096);     // n-tile 1
#pragma unroll
            for (int mt = 0; mt < 2; mt++) {
                if (mt < nmt) {
                    const unsigned short* ap = xT + (rowpx + xcol[mt][d]) * CIN + cofs;
                    bf16x8 afr = *(const bf16x8*)ap;
                    if (!xval[mt][d]) afr = (bf16x8)0;
                    acc[mt][0] = __builtin_amdgcn_mfma_f32_16x16x32_bf16(afr, b0, acc[mt][0], 0, 0, 0);
                    acc[mt][1] = __builtin_amdgcn_mfma_f32_16x16x32_bf16(afr, b1, acc[mt][1], 0, 0, 0);
                }
            }
        }
    }

    // ---- epilogue: BN + relu -> per-wave LDS tile -> fp32 conv2 matvec ----
    // acc C/D layout: col n = lane&15 (+nt*16), row pxl = (lane>>4)*4 + r.
    long rowpix = (long)b * HWDIM + (long)y * WDIM;
    int n_l = lane & 31;           // output channel handled by this lane (<28 valid)
    int half = lane >> 5;          // lanes 0-31 do px 0-7, lanes 32-63 do px 8-15
    float4 w2r[7];
#pragma unroll
    for (int jj = 0; jj < 7; jj++) {
        if (n_l < PDIM) w2r[jj] = ((const float4*)(w2 + n_l * PDIM))[jj];
        else            w2r[jj] = make_float4(0.f, 0.f, 0.f, 0.f);
    }

#pragma unroll
    for (int mt = 0; mt < 2; mt++) {
        if (mt < nmt) {
            // write relu(bn(acc)) tile: rows kg*4+r, cols nt*16+lm. cols 28..31
            // are exact zeros (scale/shift padded with 0 -> relu(0)=0).
#pragma unroll
            for (int nt = 0; nt < 2; nt++) {
                int n = nt * 16 + lm;
                float sc = scale[n], sh = shift[n];
#pragma unroll
                for (int r = 0; r < 4; r++) {
                    float v = fmaf(acc[mt][nt][r], sc, sh);
                    t2[w][kg * 4 + r][n] = v > 0.f ? v : 0.f;
                }
            }
            // intra-wave LDS dependency: compiler inserts lgkmcnt waits; all 64
            // lanes' ds_writes complete before the dependent ds_reads issue.
#pragma unroll
            for (int i = 0; i < 8; i++) {
                int pxl = half * 8 + i;
                float s = 0.f;
#pragma unroll
                for (int jj = 0; jj < 7; jj++) {
                    float4 a = *(const float4*)&t2[w][pxl][jj * 4];
                    s = fmaf(a.x, w2r[jj].x, s); s = fmaf(a.y, w2r[jj].y, s);
                    s = fmaf(a.z, w2r[jj].z, s); s = fmaf(a.w, w2r[jj].w, s);
                }
                int px = pxb + mt * 16 + pxl;
                if (n_l < PDIM) feat2[(rowpix + px) * PDIM + n_l] = s;
            }
        }
    }
}

// ---------- PS bilinear sampler on precomputed conv2 output (scalar gather) ----------
__global__ __launch_bounds__(256) void sample_kernel(const float* __restrict__ boxes,
                                                     const float* __restrict__ feat2,
                                                     float* __restrict__ out) {
    int gid = blockIdx.x * 256 + threadIdx.x;
    int box = gid >> 5;              // 32 lanes per box
    int pl = gid & 31;
    int b = box >> 11;
    float val = 0.f;
    if (pl < PDIM) {
        long bb = (long)box * 7;
        float xg = boxes[bb + 0], yg = boxes[bb + 1];
        float wg = boxes[bb + 3], lg = boxes[bb + 4];
        float rg = boxes[bb + 6];
        float ct = cosf(rg), st = sinf(rg);
        const float lxv[4] = {-0.5f, -0.16666667f, 0.16666667f, 0.5f};
        const float lyv[7] = {-0.5f, -0.33333334f, -0.16666667f, 0.f,
                               0.16666667f, 0.33333334f, 0.5f};
        int h = pl / 7, ww = pl - (pl / 7) * 7;
        float xx = lxv[h] * wg;
        float yy = lyv[ww] * lg;
        float gx = (xx * ct + yy * st + xg) * 2.5f;           // GRID_OFF.x = 0
        float gy = (yy * ct - xx * st + yg + 40.f) * 2.5f;    // GRID_OFF.y = 40
        float x0 = floorf(gx), y0 = floorf(gy);
        float fx = gx - x0, fy = gy - y0;
        int xi = (int)x0, yi = (int)y0;
        const float* base = feat2 + (long)b * HWDIM * PDIM + pl;
        float Ia = 0.f, Ib = 0.f, Ic = 0.f, Id = 0.f;
        if (yi >= 0 && yi < HDIM) {
            long r0 = (long)yi * WDIM;
            if (xi >= 0 && xi < WDIM)         Ia = base[(r0 + xi) * PDIM];
            if (xi + 1 >= 0 && xi + 1 < WDIM) Ic = base[(r0 + xi + 1) * PDIM];
        }
        if (yi + 1 >= 0 && yi + 1 < HDIM) {
            long r1 = (long)(yi + 1) * WDIM;
            if (xi >= 0 && xi < WDIM)         Ib = base[(r1 + xi) * PDIM];
            if (xi + 1 >= 0 && xi + 1 < WDIM) Id = base[(r1 + xi + 1) * PDIM];
        }
        val = (1.f - fx) * (1.f - fy) * Ia + (1.f - fx) * fy * Ib
            + fx * (1.f - fy) * Ic + fx * fy * Id;
    }
#pragma unroll
    for (int m = 16; m >= 1; m >>= 1) val += __shfl_xor(val, m, 64);
    if ((threadIdx.x & 31) == 0) {
        out[box] = val * (1.f / 28.f);
    }
}

// ---------- launch ----------
extern "C" void kernel_launch(void* const* d_in, const int* in_sizes, int n_in,
                              void* d_out, int out_size, void* d_ws, size_t ws_size,
                              hipStream_t stream) {
    const float* x     = (const float*)d_in[0];
    const float* boxes = (const float*)d_in[1];
    const float* w1    = (const float*)d_in[2];
    const float* g     = (const float*)d_in[3];
    const float* bt    = (const float*)d_in[4];
    const float* mn    = (const float*)d_in[5];
    const float* vr    = (const float*)d_in[6];
    const float* w2    = (const float*)d_in[7];
    float* out = (float*)d_out;

    char* ws = (char*)d_ws;
    unsigned short* xT  = (unsigned short*)ws;                 // 72,089,600 B
    float* feat2        = (float*)(ws + 72089600);             // 15,769,600 B
    unsigned short* BwT = (unsigned short*)(ws + 90112000);    //    147,456 B
    float* scale        = (float*)(ws + 90259456);             //        128 B
    float* shift        = (float*)(ws + 90259584);             //        128 B

    transpose_kernel<<<dim3(550, 8, 4), 256, 0, stream>>>(x, xT);
    prep_kernel<<<289, 256, 0, stream>>>(w1, g, bt, mn, vr, BwT, scale, shift);
    conv1_kernel<<<dim3(HDIM, 4), 384, 0, stream>>>(xT, BwT, scale, shift, w2, feat2);
    sample_kernel<<<1024, 256, 0, stream>>>(boxes, feat2, out);
}

// Round 2
// 380.804 us; speedup vs baseline: 1.1566x; 1.1566x over previous
//
#include <hip/hip_runtime.h>
#include <hip/hip_bf16.h>

// PSWarpHead round 8. conv1 rewrite: LDS-staged A operand.
//   transpose: fp32 x [b][c][hw] -> bf16 xT [b][hw][c]   (unchanged, validated)
//   conv1: per (b,y) block, loop 8 chunks of 32 channels:
//          stage 3 rows x 176 px x 32c of xT into LDS via global_load_lds(16B),
//          batch 9-tap B fragments into regs, MFMA from ds_read_b128.
//          Epilogue (BN+relu+conv2 matvec -> feat2[px][28]) unchanged from r7.
//   sample: 4-corner scalar gather of feat2 (unchanged from r7)
// LDS: As 3*178*32 bf16 = 34,176 B + t2 13,824 B = 48,000 B -> 3 blocks/CU.
// Accumulation order identical to r7 -> same numerics (absmax ~1e-3).

#define WDIM 176
#define HDIM 200
#define HWDIM 35200
#define CIN 256
#define PDIM 28
#define NBOX 2048

typedef __attribute__((ext_vector_type(8))) short bf16x8;
typedef __attribute__((ext_vector_type(4))) float floatx4;

__device__ __forceinline__ unsigned short f2bf(float f) {
    unsigned int u; __builtin_memcpy(&u, &f, 4);
    unsigned int r = u + 0x7FFFu + ((u >> 16) & 1u);   // RNE
    return (unsigned short)(r >> 16);
}

__device__ __forceinline__ void async_copy16(const void* g, void* l) {
    __builtin_amdgcn_global_load_lds(
        (const __attribute__((address_space(1))) void*)g,
        (__attribute__((address_space(3))) void*)l, 16, 0, 0);
}

// ---------- transpose: fp32 x [b][c][hw] -> bf16 xT [b][hw][c] ----------
__global__ __launch_bounds__(256) void transpose_kernel(const float* __restrict__ x,
                                                        unsigned short* __restrict__ xT) {
    __shared__ unsigned short tile[32][80];
    int b = blockIdx.z, c0 = blockIdx.y * 32, px0 = blockIdx.x * 64;
    int t = threadIdx.x;
    int c_l = t >> 3, pxg = (t & 7) * 8;
    const float* sp = x + (long)(b * CIN + c0 + c_l) * HWDIM + px0 + pxg;
    float4 a = ((const float4*)sp)[0], bq = ((const float4*)sp)[1];
    tile[c_l][pxg + 0] = f2bf(a.x);  tile[c_l][pxg + 1] = f2bf(a.y);
    tile[c_l][pxg + 2] = f2bf(a.z);  tile[c_l][pxg + 3] = f2bf(a.w);
    tile[c_l][pxg + 4] = f2bf(bq.x); tile[c_l][pxg + 5] = f2bf(bq.y);
    tile[c_l][pxg + 6] = f2bf(bq.z); tile[c_l][pxg + 7] = f2bf(bq.w);
    __syncthreads();
    int px_l = t >> 2, cg = (t & 3) * 8;
    ushort4 o0, o1;
    o0.x = tile[cg + 0][px_l]; o0.y = tile[cg + 1][px_l];
    o0.z = tile[cg + 2][px_l]; o0.w = tile[cg + 3][px_l];
    o1.x = tile[cg + 4][px_l]; o1.y = tile[cg + 5][px_l];
    o1.z = tile[cg + 6][px_l]; o1.w = tile[cg + 7][px_l];
    long dst = (long)(b * HWDIM + px0 + px_l) * CIN + c0 + cg;
    *(ushort4*)(xT + dst) = o0;
    *(ushort4*)(xT + dst + 4) = o1;
}

// ---------- prep: BwT[tap][n(32,pad0)][c] bf16; BN fold (fp32 in) ----------
__global__ void prep_kernel(const float* __restrict__ w1,
                            const float* __restrict__ g, const float* __restrict__ bt,
                            const float* __restrict__ mn, const float* __restrict__ vr,
                            unsigned short* __restrict__ BwT,
                            float* __restrict__ scale, float* __restrict__ shift) {
    int idx = blockIdx.x * 256 + threadIdx.x;
    if (idx < 9 * 32 * 256) {
        int tap = idx >> 13;
        int r = idx & 8191;
        int n = r >> 8, c = r & 255;
        BwT[idx] = (n < PDIM) ? f2bf(w1[n * 2304 + c * 9 + tap]) : (unsigned short)0;
    } else if (idx < 73728 + 32) {
        int p = idx - 73728;
        if (p < PDIM) {
            float inv = g[p] / sqrtf(vr[p] + 1e-3f);
            scale[p] = inv;
            shift[p] = bt[p] - mn[p] * inv;
        } else { scale[p] = 0.f; shift[p] = 0.f; }
    }
}

// ---------- conv1 (LDS-staged MFMA) + fused BN/relu/conv2 epilogue ----------
// block = (b,y) row: 6 waves, wave w -> px [w*32, w*32+32) (wave 5: 16 px).
__global__ __launch_bounds__(384) void conv1_kernel(const unsigned short* __restrict__ xT,
                                                    const unsigned short* __restrict__ BwT,
                                                    const float* __restrict__ scale,
                                                    const float* __restrict__ shift,
                                                    const float* __restrict__ w2,
                                                    float* __restrict__ feat2) {
    // A-operand stage: 3 rows x 178 px-slots (px+1, slots 0/177 = halo, masked
    // on read) x 32 ch bf16. Row stride 178*32*2 = 11392 B; px stride 64 B.
    __shared__ unsigned short As[3 * 178 * 32];
    // per-wave fp32 tile for the conv2 matvec (r7-validated)
    __shared__ float t2[6][16][36];

    int y = blockIdx.x, b = blockIdx.y;
    int lane = threadIdx.x & 63, w = threadIdx.x >> 6;
    int nmt = (w == 5) ? 1 : 2;
    int lm = lane & 15, kg = lane >> 4;
    int kg8 = kg * 8;
    int pxb = w * 32;

    bool rowok[3];
#pragma unroll
    for (int rr = 0; rr < 3; rr++) rowok[rr] = (y + rr - 1 >= 0) && (y + rr - 1 < HDIM);

    // per-(mt,d) LDS element offset of this lane's A fragment + validity
    int  aoff[2][3];
    bool xval[2][3];
#pragma unroll
    for (int mt = 0; mt < 2; mt++) {
#pragma unroll
        for (int d = 0; d < 3; d++) {
            int xp = pxb + mt * 16 + lm + (d - 1);        // -1 .. 176
            xval[mt][d] = (xp >= 0) && (xp < WDIM);
            aoff[mt][d] = (1 + xp) * 32 + kg8;            // slot px+1 in [0,178)
        }
    }

    // staging source base for this wave's row (waves 0-2 stage row w)
    const unsigned short* gsrc0 = nullptr;
    unsigned short* lbase0 = nullptr;
    if (w < 3 && rowok[w]) {
        gsrc0 = xT + ((long)(b * HDIM + y + w - 1) * WDIM + (lane >> 2)) * CIN + (lane & 3) * 8;
        lbase0 = &As[(w * 178 + 1) * 32];
    }

    floatx4 acc[2][2] = {{{0.f,0.f,0.f,0.f},{0.f,0.f,0.f,0.f}},
                         {{0.f,0.f,0.f,0.f},{0.f,0.f,0.f,0.f}}};

    for (int j = 0; j < 8; j++) {
        int c0 = j * 32;
        __syncthreads();                       // all waves done reading prev chunk
        if (gsrc0) {
            // 11 x 16B/lane = 176 px x 32 ch of row w, chunk c0
#pragma unroll
            for (int i = 0; i < 11; i++)
                async_copy16(gsrc0 + c0 + (long)i * 16 * CIN, lbase0 + i * 16 * 32);
        }
        __syncthreads();                       // stage complete (vmcnt drained)

        // batch B fragments for all 9 taps into registers (L2-hot, issued early)
        int cofs = c0 + kg8;
        bf16x8 bfr[9][2];
#pragma unroll
        for (int tap = 0; tap < 9; tap++) {
            const unsigned short* bp = BwT + ((tap * 32 + lm) << 8) + cofs;
            bfr[tap][0] = *(const bf16x8*)bp;
            bfr[tap][1] = *(const bf16x8*)(bp + 4096);   // n-tile 1
        }

#pragma unroll
        for (int tap = 0; tap < 9; tap++) {
            int rr = tap / 3, d = tap % 3;
            if (!rowok[rr]) continue;          // block-uniform
            int rbase = rr * (178 * 32);
#pragma unroll
            for (int mt = 0; mt < 2; mt++) {
                if (mt < nmt) {
                    bf16x8 afr = *(const bf16x8*)&As[rbase + aoff[mt][d]];
                    if (!xval[mt][d]) afr = (bf16x8)0;
                    acc[mt][0] = __builtin_amdgcn_mfma_f32_16x16x32_bf16(afr, bfr[tap][0], acc[mt][0], 0, 0, 0);
                    acc[mt][1] = __builtin_amdgcn_mfma_f32_16x16x32_bf16(afr, bfr[tap][1], acc[mt][1], 0, 0, 0);
                }
            }
        }
    }

    // ---- epilogue: BN + relu -> per-wave LDS tile -> fp32 conv2 matvec ----
    // acc C/D layout: col n = lane&15 (+nt*16), row pxl = (lane>>4)*4 + r.
    long rowpix = (long)b * HWDIM + (long)y * WDIM;
    int n_l = lane & 31;           // output channel handled by this lane (<28 valid)
    int half = lane >> 5;          // lanes 0-31 do px 0-7, lanes 32-63 do px 8-15
    float4 w2r[7];
#pragma unroll
    for (int jj = 0; jj < 7; jj++) {
        if (n_l < PDIM) w2r[jj] = ((const float4*)(w2 + n_l * PDIM))[jj];
        else            w2r[jj] = make_float4(0.f, 0.f, 0.f, 0.f);
    }

#pragma unroll
    for (int mt = 0; mt < 2; mt++) {
        if (mt < nmt) {
#pragma unroll
            for (int nt = 0; nt < 2; nt++) {
                int n = nt * 16 + lm;
                float sc = scale[n], sh = shift[n];
#pragma unroll
                for (int r = 0; r < 4; r++) {
                    float v = fmaf(acc[mt][nt][r], sc, sh);
                    t2[w][kg * 4 + r][n] = v > 0.f ? v : 0.f;
                }
            }
            // intra-wave LDS dependency: compiler inserts lgkmcnt waits.
#pragma unroll
            for (int i = 0; i < 8; i++) {
                int pxl = half * 8 + i;
                float s = 0.f;
#pragma unroll
                for (int jj = 0; jj < 7; jj++) {
                    float4 a = *(const float4*)&t2[w][pxl][jj * 4];
                    s = fmaf(a.x, w2r[jj].x, s); s = fmaf(a.y, w2r[jj].y, s);
                    s = fmaf(a.z, w2r[jj].z, s); s = fmaf(a.w, w2r[jj].w, s);
                }
                int px = pxb + mt * 16 + pxl;
                if (n_l < PDIM) feat2[(rowpix + px) * PDIM + n_l] = s;
            }
        }
    }
}

// ---------- PS bilinear sampler on precomputed conv2 output (scalar gather) ----------
__global__ __launch_bounds__(256) void sample_kernel(const float* __restrict__ boxes,
                                                     const float* __restrict__ feat2,
                                                     float* __restrict__ out) {
    int gid = blockIdx.x * 256 + threadIdx.x;
    int box = gid >> 5;              // 32 lanes per box
    int pl = gid & 31;
    int b = box >> 11;
    float val = 0.f;
    if (pl < PDIM) {
        long bb = (long)box * 7;
        float xg = boxes[bb + 0], yg = boxes[bb + 1];
        float wg = boxes[bb + 3], lg = boxes[bb + 4];
        float rg = boxes[bb + 6];
        float ct = cosf(rg), st = sinf(rg);
        const float lxv[4] = {-0.5f, -0.16666667f, 0.16666667f, 0.5f};
        const float lyv[7] = {-0.5f, -0.33333334f, -0.16666667f, 0.f,
                               0.16666667f, 0.33333334f, 0.5f};
        int h = pl / 7, ww = pl - (pl / 7) * 7;
        float xx = lxv[h] * wg;
        float yy = lyv[ww] * lg;
        float gx = (xx * ct + yy * st + xg) * 2.5f;           // GRID_OFF.x = 0
        float gy = (yy * ct - xx * st + yg + 40.f) * 2.5f;    // GRID_OFF.y = 40
        float x0 = floorf(gx), y0 = floorf(gy);
        float fx = gx - x0, fy = gy - y0;
        int xi = (int)x0, yi = (int)y0;
        const float* base = feat2 + (long)b * HWDIM * PDIM + pl;
        float Ia = 0.f, Ib = 0.f, Ic = 0.f, Id = 0.f;
        if (yi >= 0 && yi < HDIM) {
            long r0 = (long)yi * WDIM;
            if (xi >= 0 && xi < WDIM)         Ia = base[(r0 + xi) * PDIM];
            if (xi + 1 >= 0 && xi + 1 < WDIM) Ic = base[(r0 + xi + 1) * PDIM];
        }
        if (yi + 1 >= 0 && yi + 1 < HDIM) {
            long r1 = (long)(yi + 1) * WDIM;
            if (xi >= 0 && xi < WDIM)         Ib = base[(r1 + xi) * PDIM];
            if (xi + 1 >= 0 && xi + 1 < WDIM) Id = base[(r1 + xi + 1) * PDIM];
        }
        val = (1.f - fx) * (1.f - fy) * Ia + (1.f - fx) * fy * Ib
            + fx * (1.f - fy) * Ic + fx * fy * Id;
    }
#pragma unroll
    for (int m = 16; m >= 1; m >>= 1) val += __shfl_xor(val, m, 64);
    if ((threadIdx.x & 31) == 0) {
        out[box] = val * (1.f / 28.f);
    }
}

// ---------- launch ----------
extern "C" void kernel_launch(void* const* d_in, const int* in_sizes, int n_in,
                              void* d_out, int out_size, void* d_ws, size_t ws_size,
                              hipStream_t stream) {
    const float* x     = (const float*)d_in[0];
    const float* boxes = (const float*)d_in[1];
    const float* w1    = (const float*)d_in[2];
    const float* g     = (const float*)d_in[3];
    const float* bt    = (const float*)d_in[4];
    const float* mn    = (const float*)d_in[5];
    const float* vr    = (const float*)d_in[6];
    const float* w2    = (const float*)d_in[7];
    float* out = (float*)d_out;

    char* ws = (char*)d_ws;
    unsigned short* xT  = (unsigned short*)ws;                 // 72,089,600 B
    float* feat2        = (float*)(ws + 72089600);             // 15,769,600 B
    unsigned short* BwT = (unsigned short*)(ws + 90112000);    //    147,456 B
    float* scale        = (float*)(ws + 90259456);             //        128 B
    float* shift        = (float*)(ws + 90259584);             //        128 B

    transpose_kernel<<<dim3(550, 8, 4), 256, 0, stream>>>(x, xT);
    prep_kernel<<<289, 256, 0, stream>>>(w1, g, bt, mn, vr, BwT, scale, shift);
    conv1_kernel<<<dim3(HDIM, 4), 384, 0, stream>>>(xT, BwT, scale, shift, w2, feat2);
    sample_kernel<<<1024, 256, 0, stream>>>(boxes, feat2, out);
}